// Round 10
// baseline (212.586 us; speedup 1.0000x reference)
//
#include <hip/hip_runtime.h>

// ---------------------------------------------------------------------------
// QuantizedShaper: B=256, L=8192, DIM=256, NPAT=64, HIST=32, WIN=8, T=1024.
//
// R21 = R18 skeleton + pipelined single-pass top-2 scan.
// Model (fits R12-R20): step cost ~= serialized-reduce-completions x ~250cyc;
// internals of the reduce are irrelevant (lone wave eats all dep stalls).
// R21 keeps ONE reduce per step but overlaps TWO in flight:
//   h_{i+2} = U[i+2] - C_i  (launchable at resolve(i))
//   top-2 of h in ONE butterfly pass: per hop (m,s) <- (max(m,m'),
//   max3(min(m,m'), s, s')) over the validated 6-stage topology.
//   v_i = h_i - onehot(w_{i-1})  =>  winner_i in {argmax(h_i), second(h_i)}:
//     mwin = (mH & mprev) ? ((B > A-1) ? mH2 : mH) : mH
//   (ballot+SALU resolution -- proven ~free in R12; A-1.0f is the validated
//   exact vA-1; tie-free assumption as R6-R20, absmax 0.0 throughout).
//   C/bm updates via v_cndmask with the SGPR-pair mask (1 VALU each).
// Reduce latency amortizes /2; the two butterflies are independent chains
// that fill each other's issue bubbles. Chunk prologue restarts the pipe
// (2 independent reduces, ~5us total). Fill/extract/epilogue = R18 verbatim.
// ---------------------------------------------------------------------------

constexpr int Bb = 256, Ll = 8192, DIMc = 256, NPAT = 64, HIST = 32, WINc = 8;
constexpr int Tt = Ll / WINc;   // 1024
constexpr int TC = 32;          // t-chunk
constexpr int NC = Tt / TC;     // 32 chunks
constexpr float CINV = 1.0f / 64.0f;

#define DPP_ADDF(s, ctrl, rmask)                                               \
  do {                                                                         \
    int _si = __float_as_int(s);                                               \
    int _ti = __builtin_amdgcn_update_dpp(_si, _si, (ctrl), (rmask), 0xF, false); \
    (s) += __int_as_float(_ti);                                                \
  } while (0)

#if defined(__has_builtin)
#if __has_builtin(__builtin_amdgcn_permlane16_swap)
#define HAVE_PL16 1
#endif
#if __has_builtin(__builtin_amdgcn_permlane32_swap)
#define HAVE_PL32 1
#endif
#endif

// per-lane select by bit[lane] of an SGPR-pair mask (1 VALU, no VCC juggling)
__device__ __forceinline__ float sel_f(float a, float b, unsigned long long m) {
  float r;
  asm("v_cndmask_b32 %0, %1, %2, %3" : "=v"(r) : "v"(a), "v"(b), "s"(m));
  return r;
}
__device__ __forceinline__ unsigned sel_u(unsigned a, unsigned b,
                                          unsigned long long m) {
  unsigned r;
  asm("v_cndmask_b32 %0, %1, %2, %3" : "=v"(r) : "v"(a), "v"(b), "s"(m));
  return r;
}

// Single-pass wave-wide top-2: A = max, B = second (all lanes).
// Topology = validated wave_max64 stages (R14/R16/R18, absmax 0.0); per hop
// carries (m,s): m' = partner m, s' = partner s;
//   m <- max(m,m');  s <- max(min(m_old,m'), s, s').
__device__ __forceinline__ void top2_64(float h, float& A, float& B) {
  float m = h;
  float s = __int_as_float(0xff800000);  // -inf
#define T2_DPP(ctrl)                                                           \
  {                                                                            \
    int mi = __float_as_int(m), si = __float_as_int(s);                        \
    float tm = __int_as_float(                                                 \
        __builtin_amdgcn_update_dpp(mi, mi, (ctrl), 0xF, 0xF, false));         \
    float ts = __int_as_float(                                                 \
        __builtin_amdgcn_update_dpp(si, si, (ctrl), 0xF, 0xF, false));         \
    float mn = fminf(m, tm);                                                   \
    m = fmaxf(m, tm);                                                          \
    s = fmaxf(fmaxf(s, ts), mn);                                               \
  }
  T2_DPP(0xB1)   // xor1
  T2_DPP(0x4E)   // xor2
  T2_DPP(0x141)  // row_half_mirror
  T2_DPP(0x140)  // row_mirror -> 16-row top-2
#undef T2_DPP
#if defined(HAVE_PL16)
  {
    auto r = __builtin_amdgcn_permlane16_swap(__float_as_int(m),
                                              __float_as_int(m), false, false);
    auto rs = __builtin_amdgcn_permlane16_swap(__float_as_int(s),
                                               __float_as_int(s), false, false);
    float a = __int_as_float(r[0]), b = __int_as_float(r[1]);
    float sa = __int_as_float(rs[0]), sb = __int_as_float(rs[1]);
    float mn = fminf(a, b);          // min(own m, partner m)
    m = fmaxf(a, b);                 // max(own m, partner m)
    s = fmaxf(fmaxf(sa, sb), mn);    // max(own s, partner s, mn)
  }
#else
  {
    float tm = __int_as_float(
        __builtin_amdgcn_ds_swizzle(__float_as_int(m), 0x401F));
    float ts = __int_as_float(
        __builtin_amdgcn_ds_swizzle(__float_as_int(s), 0x401F));
    float mn = fminf(m, tm);
    m = fmaxf(m, tm);
    s = fmaxf(fmaxf(s, ts), mn);
  }
#endif
#if defined(HAVE_PL32)
  {
    auto r = __builtin_amdgcn_permlane32_swap(__float_as_int(m),
                                              __float_as_int(m), false, false);
    auto rs = __builtin_amdgcn_permlane32_swap(__float_as_int(s),
                                               __float_as_int(s), false, false);
    float a = __int_as_float(r[0]), b = __int_as_float(r[1]);
    float sa = __int_as_float(rs[0]), sb = __int_as_float(rs[1]);
    float mn = fminf(a, b);
    m = fmaxf(a, b);
    s = fmaxf(fmaxf(sa, sb), mn);
  }
#else
  {
    int lane = (int)(threadIdx.x & 63);
    float tm = __int_as_float(__builtin_amdgcn_ds_bpermute(
        ((lane ^ 32) << 2), __float_as_int(m)));
    float ts = __int_as_float(__builtin_amdgcn_ds_bpermute(
        ((lane ^ 32) << 2), __float_as_int(s)));
    float mn = fminf(m, tm);
    m = fmaxf(m, tm);
    s = fmaxf(fmaxf(s, ts), mn);
  }
#endif
  A = m;
  B = s;
}

// one block per pattern p: W2[p,0..31] + bias2[p]
__global__ __launch_bounds__(256) void precompute_kernel(
    const float* __restrict__ conv_w, const float* __restrict__ conv_b,
    const float* __restrict__ keys_w, float* __restrict__ wsf) {
  __shared__ float part[8][32];
  __shared__ float bred[4];
  const int p = blockIdx.x;
  const int t = threadIdx.x;
  const int h = t & 31, g = t >> 5;
  const float* kwp = keys_w + (size_t)p * DIMc;

  float acc = 0.f;
#pragma unroll
  for (int dd = 0; dd < 32; ++dd) {
    int d = g * 32 + dd;
    acc = fmaf(kwp[d], conv_w[d * HIST + h], acc);
  }
  part[g][h] = acc;

  float bp = kwp[t] * conv_b[t];
#pragma unroll
  for (int off = 32; off; off >>= 1) bp += __shfl_down(bp, off);
  if ((t & 63) == 0) bred[t >> 6] = bp;
  __syncthreads();

  if (t < 32) {
    float s = 0.f;
#pragma unroll
    for (int gg = 0; gg < 8; ++gg) s += part[gg][t];
    wsf[(t >> 2) * (NPAT * 4) + p * 4 + (t & 3)] = s;  // float4-friendly
  } else if (t == 32) {
    wsf[NPAT * HIST + p] = (bred[0] + bred[1]) + (bred[2] + bred[3]);
  }
}

__global__ __launch_bounds__(256) void shaper_kernel(
    const float* __restrict__ x, const float* __restrict__ avg_init,
    const float* __restrict__ shapes_w, const float* __restrict__ wsf,
    float* __restrict__ out) {
  __shared__ __align__(16) float xpad[HIST - 1 + Ll + 1];
  __shared__ float scb[2][TC * NPAT];
  __shared__ unsigned int bmbuf[2][64];   // per-lane win masks, dbuf
  __shared__ unsigned char idx8[Tt];      // winner pattern per step
  __shared__ float shp[WINc * NPAT];

  const int b    = blockIdx.x;
  const int tid  = threadIdx.x;
  const int wid  = tid >> 6;
  const int lane = tid & 63;
  const float* xrow = x + (size_t)b * Ll;

  // ---- stage x (left-padded) + shapes into LDS (all waves) ----
  if (tid < HIST - 1) xpad[tid] = 0.f;
  {
    const float4* xv4 = (const float4*)xrow;
#pragma unroll
    for (int k = 0; k < 8; ++k) {
      int i4 = k * 256 + tid;
      float4 v = xv4[i4];
      float* dst = xpad + HIST - 1 + i4 * 4;
      dst[0] = v.x; dst[1] = v.y; dst[2] = v.z; dst[3] = v.w;
    }
  }
  for (int i = tid; i < WINc * NPAT; i += 256) shp[i] = shapes_w[i];

  // ---- av0 via DPP-sum butterfly (all waves; validated R5/R8/R10) ----
  float av0;
  {
    float s = avg_init[(size_t)b * NPAT + lane];
    float t = s;
    DPP_ADDF(t, 0xB1, 0xF);
    DPP_ADDF(t, 0x4E, 0xF);
    DPP_ADDF(t, 0x141, 0xF);
    DPP_ADDF(t, 0x140, 0xF);
    DPP_ADDF(t, 0x142, 0xA);
    DPP_ADDF(t, 0x143, 0xC);   // lane63 = total
    float tot = __int_as_float(__builtin_amdgcn_readlane(__float_as_int(t), 63));
    av0 = s - tot * CINV;
  }

  __syncthreads();  // S1: staging complete (both paths)

  if (wid == 0) {
    // =====================================================================
    // SCAN PATH (wave 0): pipelined top-2, 2 reduces in flight.
    // =====================================================================
    float C = 0.f;
    __syncthreads();  // S2: fill(0) done

    for (int c = 0; c < NC; ++c) {
      const float* sb = scb[c & 1];
      // U ring (8 deep, SSA under full unroll)
      float ur[8];
#pragma unroll
      for (int k = 0; k < 8; ++k) ur[k] = sb[k * NPAT + lane];
      unsigned bm = 0u;
      unsigned long long mprev = 0ull;

      // ---- prologue: stats for steps 0 and 1 (independent, both use C) ----
      float h0 = ur[0] - C;      // v_0 exactly (no pending decrement)
      float h1 = ur[1] - C;      // pending = {w_0} at resolve time
      float A0, B0, A1, B1;
      top2_64(h0, A0, B0);
      top2_64(h1, A1, B1);
      {  // resolve step 0: mprev = 0 -> winner = argmax(h0)
        unsigned long long mwin = __ballot(h0 == A0);
        float C1 = C + 1.0f;
        C = sel_f(C, C1, mwin);
        bm = sel_u(bm, bm | 1u, mwin);
        mprev = mwin;
        h0 = ur[2] - C;          // stats for step 2 (slot 0)
        top2_64(h0, A0, B0);
      }

      // ---- steady loop: resolve i (slot i&1), launch stats for i+2 ----
#pragma unroll
      for (int i = 1; i < TC; ++i) {
        if (i + 7 < TC) ur[(i + 7) & 7] = sb[(i + 7) * NPAT + lane];
        float hC = (i & 1) ? h1 : h0;
        float Ac = (i & 1) ? A1 : A0;
        float Bc = (i & 1) ? B1 : B0;
        unsigned long long mH  = __ballot(hC == Ac);
        unsigned long long mH2 = __ballot(hC == Bc);
        bool gt = __ballot(Bc > Ac - 1.0f) != 0ull;  // exact vA-1 compare
        unsigned long long mwin =
            ((mH & mprev) != 0ull) ? (gt ? mH2 : mH) : mH;
        float C1 = C + 1.0f;
        C = sel_f(C, C1, mwin);
        bm = sel_u(bm, bm | (1u << i), mwin);
        mprev = mwin;
        if (i + 2 < TC) {
          float hn = ur[(i + 2) & 7] - C;
          if (i & 1) { h1 = hn; top2_64(h1, A1, B1); }
          else       { h0 = hn; top2_64(h0, A0, B0); }
        }
      }
      bmbuf[c & 1][lane] = bm;
      __syncthreads();  // S3..S34
    }
    __syncthreads();  // S35: final extract done
  } else {
    // =====================================================================
    // FILL + EXTRACT PATH (waves 1-3) -- R18 verbatim.
    // =====================================================================
    float4 w2v[8];
    {
      const float4* w2g = (const float4*)wsf;
#pragma unroll
      for (int h4 = 0; h4 < 8; ++h4) w2v[h4] = w2g[h4 * 64 + lane];
    }
    float b2 = wsf[NPAT * HIST + lane];

    // fill chunk c (bitwise-identical to R12-R20; do not touch fma order)
    auto fill = [&](int c, float* __restrict__ sb) {
      int base = c * TC;
      for (int tl = wid - 1; tl < TC; tl += 3) {
        int t = base + tl;
        const float4* xw = (const float4*)(xpad + t * WINc);  // 32B-aligned
        float acc = b2;
#pragma unroll
        for (int h4 = 0; h4 < 8; ++h4) {
          float4 xv = xw[h4];
          float4 wv = w2v[h4];
          acc = fmaf(xv.x, wv.x, acc);
          acc = fmaf(xv.y, wv.y, acc);
          acc = fmaf(xv.z, wv.z, acc);
          acc = fmaf(xv.w, wv.w, acc);
        }
        float sc = fminf(fmaxf(acc, 0.f), 6.f);
        sb[tl * NPAT + lane] = (sc - av0) + (float)t * CINV;
      }
    };

    // batched winner extraction for chunk cc, split across waves 1-3
    auto extract3 = [&](int cc) {
      unsigned int mv = bmbuf[cc & 1][lane];
      for (int i = wid - 1; i < TC; i += 3) {
        unsigned long long mk = __ballot(((mv >> i) & 1u) != 0u);
        int w = (int)(__ffsll(mk) - 1);
        if (lane == 0) idx8[cc * TC + i] = (unsigned char)w;
      }
    };

    fill(0, scb[0]);
    __syncthreads();  // S2

    for (int c = 0; c < NC; ++c) {
      if (c + 1 < NC) fill(c + 1, scb[(c + 1) & 1]);
      if (c >= 1) extract3(c - 1);
      __syncthreads();  // S3..S34
    }
    extract3(NC - 1);
    __syncthreads();  // S35
  }

  // ---- epilogue: out[b,l] = relu(shapes[l&7, idx[l>>3]] - x[b,l]) ----
  float4* outv = (float4*)(out + (size_t)b * Ll);
#pragma unroll
  for (int k = 0; k < 8; ++k) {
    int i4 = k * 256 + tid;
    int l0 = i4 * 4;
    int t  = l0 >> 3;
    int w0 = l0 & 7;
    int p  = (int)idx8[t];
    float4 o;
    o.x = fmaxf(shp[(w0 + 0) * NPAT + p] - xpad[HIST - 1 + l0 + 0], 0.f);
    o.y = fmaxf(shp[(w0 + 1) * NPAT + p] - xpad[HIST - 1 + l0 + 1], 0.f);
    o.z = fmaxf(shp[(w0 + 2) * NPAT + p] - xpad[HIST - 1 + l0 + 2], 0.f);
    o.w = fmaxf(shp[(w0 + 3) * NPAT + p] - xpad[HIST - 1 + l0 + 3], 0.f);
    outv[i4] = o;
  }
}

extern "C" void kernel_launch(void* const* d_in, const int* in_sizes, int n_in,
                              void* d_out, int out_size, void* d_ws, size_t ws_size,
                              hipStream_t stream) {
  const float* x        = (const float*)d_in[0];
  const float* avg_init = (const float*)d_in[1];
  const float* conv_w   = (const float*)d_in[2];
  const float* conv_b   = (const float*)d_in[3];
  const float* keys_w   = (const float*)d_in[4];
  const float* shapes_w = (const float*)d_in[5];
  float* wsf = (float*)d_ws;

  precompute_kernel<<<NPAT, 256, 0, stream>>>(conv_w, conv_b, keys_w, wsf);
  shaper_kernel<<<Bb, 256, 0, stream>>>(x, avg_init, shapes_w, wsf,
                                        (float*)d_out);
}

// Round 11
// 180.964 us; speedup vs baseline: 1.1747x; 1.1747x over previous
//
#include <hip/hip_runtime.h>

// ---------------------------------------------------------------------------
// QuantizedShaper: B=256, L=8192, DIM=256, NPAT=64, HIST=32, WIN=8, T=1024.
//
// R22 = R18 skeleton + HALF-WAVE-PAIRED scan: one butterfly per TWO steps.
// Model (11 rounds): step ~ 200cyc serial cross-lane chain + ~2-3/instr;
// ILP pipelining (R13/R21) lost to resolution+issue cost. R22 uses LANE
// parallelism instead: patterns packed 2/lane in each 32-half; lanes 0-31
// reduce step 2k's v while lanes 32-63 reduce step 2k+1's h = U-C_{2k-1}
// IN THE SAME INSTRUCTIONS (hops half-confined: xor1/xor2/hm/mirror DPP +
// permlane16_swap; top-2 carry (m,s) per hop -- exact fmax/fmin network).
// Cross-half exchange: 2x ds_bpermute lane^32 (exact partner). Resolution
// per pair (R13/R21-validated algebra, absmax 0.0 twice):
//   e_2k    = mask01(A_v - v)            (float-mask, R16+, exact)
//   q       = e0*[h0==A_h] + e1*[h1==A_h];  b = ballot(q>0) != 0
//   gmax    = b ? max(A_h - 1, B_h) : A_h   (A_h-1 exact)
//   e_2k+1  = mask01(gmax - (h - e_2k))
// Both halves hold U for BOTH steps of the pair and update identical C
// per pattern -> state consistent; L-half writes pattern-major win masks
// (extraction/epilogue = R18 verbatim). ONE ballot per pair.
// ---------------------------------------------------------------------------

constexpr int Bb = 256, Ll = 8192, DIMc = 256, NPAT = 64, HIST = 32, WINc = 8;
constexpr int Tt = Ll / WINc;   // 1024
constexpr int TC = 32;          // t-chunk
constexpr int NC = Tt / TC;     // 32 chunks
constexpr float CINV = 1.0f / 64.0f;

#define DPP_ADDF(s, ctrl, rmask)                                               \
  do {                                                                         \
    int _si = __float_as_int(s);                                               \
    int _ti = __builtin_amdgcn_update_dpp(_si, _si, (ctrl), (rmask), 0xF, false); \
    (s) += __int_as_float(_ti);                                                \
  } while (0)

#if defined(__has_builtin)
#if __has_builtin(__builtin_amdgcn_permlane16_swap)
#define HAVE_PL16 1
#endif
#if __has_builtin(__builtin_amdgcn_fmed3f)
#define HAVE_MED3 1
#endif
#endif

__device__ __forceinline__ float clamp01(float t) {
#if defined(HAVE_MED3)
  return __builtin_amdgcn_fmed3f(t, 0.0f, 1.0f);
#else
  return fminf(fmaxf(t, 0.0f), 1.0f);
#endif
}

// exact 0/1 indicator of d == +0, for d >= 0 (validated R16-R20)
__device__ __forceinline__ float emask(float d) {
  constexpr float SC75 = 37778931862957161709568.0f;  // 2^75
  return clamp01(__builtin_fmaf(d * SC75, -SC75, 1.0f));
}

// one block per pattern p: W2[p,0..31] + bias2[p]
__global__ __launch_bounds__(256) void precompute_kernel(
    const float* __restrict__ conv_w, const float* __restrict__ conv_b,
    const float* __restrict__ keys_w, float* __restrict__ wsf) {
  __shared__ float part[8][32];
  __shared__ float bred[4];
  const int p = blockIdx.x;
  const int t = threadIdx.x;
  const int h = t & 31, g = t >> 5;
  const float* kwp = keys_w + (size_t)p * DIMc;

  float acc = 0.f;
#pragma unroll
  for (int dd = 0; dd < 32; ++dd) {
    int d = g * 32 + dd;
    acc = fmaf(kwp[d], conv_w[d * HIST + h], acc);
  }
  part[g][h] = acc;

  float bp = kwp[t] * conv_b[t];
#pragma unroll
  for (int off = 32; off; off >>= 1) bp += __shfl_down(bp, off);
  if ((t & 63) == 0) bred[t >> 6] = bp;
  __syncthreads();

  if (t < 32) {
    float s = 0.f;
#pragma unroll
    for (int gg = 0; gg < 8; ++gg) s += part[gg][t];
    wsf[(t >> 2) * (NPAT * 4) + p * 4 + (t & 3)] = s;  // float4-friendly
  } else if (t == 32) {
    wsf[NPAT * HIST + p] = (bred[0] + bred[1]) + (bred[2] + bred[3]);
  }
}

__global__ __launch_bounds__(256) void shaper_kernel(
    const float* __restrict__ x, const float* __restrict__ avg_init,
    const float* __restrict__ shapes_w, const float* __restrict__ wsf,
    float* __restrict__ out) {
  __shared__ __align__(16) float xpad[HIST - 1 + Ll + 1];
  __shared__ float scb[2][TC * NPAT];
  __shared__ unsigned int bmbuf[2][64];   // pattern-major win masks, dbuf
  __shared__ unsigned char idx8[Tt];      // winner pattern per step
  __shared__ float shp[WINc * NPAT];

  const int b    = blockIdx.x;
  const int tid  = threadIdx.x;
  const int wid  = tid >> 6;
  const int lane = tid & 63;
  const float* xrow = x + (size_t)b * Ll;

  // ---- stage x (left-padded) + shapes into LDS (all waves) ----
  if (tid < HIST - 1) xpad[tid] = 0.f;
  {
    const float4* xv4 = (const float4*)xrow;
#pragma unroll
    for (int k = 0; k < 8; ++k) {
      int i4 = k * 256 + tid;
      float4 v = xv4[i4];
      float* dst = xpad + HIST - 1 + i4 * 4;
      dst[0] = v.x; dst[1] = v.y; dst[2] = v.z; dst[3] = v.w;
    }
  }
  for (int i = tid; i < WINc * NPAT; i += 256) shp[i] = shapes_w[i];

  // ---- av0 via DPP-sum butterfly (all waves; validated R5/R8/R10) ----
  float av0;
  {
    float s = avg_init[(size_t)b * NPAT + lane];
    float t = s;
    DPP_ADDF(t, 0xB1, 0xF);
    DPP_ADDF(t, 0x4E, 0xF);
    DPP_ADDF(t, 0x141, 0xF);
    DPP_ADDF(t, 0x140, 0xF);
    DPP_ADDF(t, 0x142, 0xA);
    DPP_ADDF(t, 0x143, 0xC);   // lane63 = total
    float tot = __int_as_float(__builtin_amdgcn_readlane(__float_as_int(t), 63));
    av0 = s - tot * CINV;
  }

  __syncthreads();  // S1: staging complete (both paths)

  if (wid == 0) {
    // =====================================================================
    // SCAN PATH (wave 0): half-wave-paired, one butterfly per 2 steps.
    // lane l: half = l>>5, l5 = l&31, patterns {2*l5, 2*l5+1}.
    // =====================================================================
    const int  l5 = lane & 31;
    const bool hi = (lane >= 32);
    float C0 = 0.f, C1 = 0.f;
    __syncthreads();  // S2: fill(0) done

    for (int c = 0; c < NC; ++c) {
      const float* sb = scb[c & 1];
      float2 ur[8];
#pragma unroll
      for (int t = 0; t < 8; ++t)
        ur[t] = *(const float2*)(sb + t * NPAT + 2 * l5);
      float bm0lo = 0.f, bm0hi = 0.f, bm1lo = 0.f, bm1hi = 0.f;

#pragma unroll
      for (int k = 0; k < 16; ++k) {
        const int t0 = 2 * k, t1 = 2 * k + 1;
        float2 u0 = ur[t0 & 7];
        float2 u1 = ur[t1 & 7];
        if (t0 + 8 < TC) ur[t0 & 7] = *(const float2*)(sb + (t0 + 8) * NPAT + 2 * l5);
        if (t1 + 8 < TC) ur[t1 & 7] = *(const float2*)(sb + (t1 + 8) * NPAT + 2 * l5);
        // per-slot values for both steps of the pair (both halves)
        float v0 = u0.x - C0, v1 = u0.y - C1;   // step t0
        float h0 = u1.x - C0, h1 = u1.y - C1;   // step t1 (pre-winner)
        // joint butterfly input: L-half reduces v, U-half reduces h
        float x0 = hi ? h0 : v0;
        float x1 = hi ? h1 : v1;
        float m = fmaxf(x0, x1);
        float s = fminf(x0, x1);
        // 5 half-confined top-2 hops (exact fmax/fmin network)
#define T2HOP(ctrl)                                                            \
        {                                                                      \
          int mi = __float_as_int(m), si = __float_as_int(s);                  \
          float tm = __int_as_float(                                           \
              __builtin_amdgcn_update_dpp(mi, mi, (ctrl), 0xF, 0xF, false));   \
          float ts = __int_as_float(                                           \
              __builtin_amdgcn_update_dpp(si, si, (ctrl), 0xF, 0xF, false));   \
          float mn = fminf(m, tm);                                             \
          m = fmaxf(m, tm);                                                    \
          s = fmaxf(fmaxf(s, ts), mn);                                         \
        }
        T2HOP(0xB1)   // xor1 (quad)
        T2HOP(0x4E)   // xor2 (quad)
        T2HOP(0x141)  // row_half_mirror
        T2HOP(0x140)  // row_mirror -> 16-row top-2
#undef T2HOP
#if defined(HAVE_PL16)
        {  // 16-row swap within each 32-half (order-insensitive merge)
          auto r  = __builtin_amdgcn_permlane16_swap(__float_as_int(m),
                                                     __float_as_int(m), false, false);
          auto rs = __builtin_amdgcn_permlane16_swap(__float_as_int(s),
                                                     __float_as_int(s), false, false);
          float a = __int_as_float(r[0]),  b2 = __int_as_float(r[1]);
          float sa = __int_as_float(rs[0]), sb2 = __int_as_float(rs[1]);
          float mn = fminf(a, b2);
          m = fmaxf(a, b2);
          s = fmaxf(fmaxf(sa, sb2), mn);
        }
#else
        {  // lane^16 partner via ds_swizzle (exact)
          float tm = __int_as_float(
              __builtin_amdgcn_ds_swizzle(__float_as_int(m), 0x401F));
          float ts = __int_as_float(
              __builtin_amdgcn_ds_swizzle(__float_as_int(s), 0x401F));
          float mn = fminf(m, tm);
          m = fmaxf(m, tm);
          s = fmaxf(fmaxf(s, ts), mn);
        }
#endif
        // cross-half exchange: exact partner via bpermute lane^32
        float pM = __int_as_float(__builtin_amdgcn_ds_bpermute(
            ((lane ^ 32) << 2), __float_as_int(m)));
        float pS = __int_as_float(__builtin_amdgcn_ds_bpermute(
            ((lane ^ 32) << 2), __float_as_int(s)));
        float A_v = hi ? pM : m;   // top of v (step t0)
        float A_h = hi ? m : pM;   // top of h (step t1)
        float B_h = hi ? s : pS;   // second of h

        // resolve step t0 (float-mask; d >= 0, ==+0 iff winner)
        float e0 = emask(A_v - v0);
        float e1 = emask(A_v - v1);
        C0 += e0; C1 += e1;
        if (k < 8) {
          bm0lo = __builtin_fmaf(e0, (float)(1u << t0), bm0lo);
          bm1lo = __builtin_fmaf(e1, (float)(1u << t0), bm1lo);
        } else {
          bm0hi = __builtin_fmaf(e0, (float)(1u << (t0 - 16)), bm0hi);
          bm1hi = __builtin_fmaf(e1, (float)(1u << (t0 - 16)), bm1hi);
        }
        // was winner also argmax of h?  (one ballot per pair)
        float mh0 = emask(A_h - h0);
        float mh1 = emask(A_h - h1);
        float q = __builtin_fmaf(e1, mh1, e0 * mh0);
        unsigned long long mq = __ballot(q > 0.0f);
        float galt = fmaxf(A_h - 1.0f, B_h);   // A_h-1 exact (validated)
        float gmax = (mq != 0ull) ? galt : A_h;
        // resolve step t1: v' = h - e  (per-lane)
        float w0 = h0 - e0;
        float w1 = h1 - e1;
        float f0 = emask(gmax - w0);
        float f1 = emask(gmax - w1);
        C0 += f0; C1 += f1;
        if (k < 8) {
          bm0lo = __builtin_fmaf(f0, (float)(1u << t1), bm0lo);
          bm1lo = __builtin_fmaf(f1, (float)(1u << t1), bm1lo);
        } else {
          bm0hi = __builtin_fmaf(f0, (float)(1u << (t1 - 16)), bm0hi);
          bm1hi = __builtin_fmaf(f1, (float)(1u << (t1 - 16)), bm1hi);
        }
      }
      if (lane < 32) {  // pattern-major masks (identical in both halves)
        bmbuf[c & 1][2 * l5 + 0] =
            (unsigned int)bm0lo | ((unsigned int)bm0hi << 16);
        bmbuf[c & 1][2 * l5 + 1] =
            (unsigned int)bm1lo | ((unsigned int)bm1hi << 16);
      }
      __syncthreads();  // S3..S34
    }
    __syncthreads();  // S35: final extract done
  } else {
    // =====================================================================
    // FILL + EXTRACT PATH (waves 1-3) -- R18 verbatim.
    // =====================================================================
    float4 w2v[8];
    {
      const float4* w2g = (const float4*)wsf;
#pragma unroll
      for (int h4 = 0; h4 < 8; ++h4) w2v[h4] = w2g[h4 * 64 + lane];
    }
    float b2 = wsf[NPAT * HIST + lane];

    // fill chunk c (bitwise-identical to R12-R21; do not touch fma order)
    auto fill = [&](int c, float* __restrict__ sb) {
      int base = c * TC;
      for (int tl = wid - 1; tl < TC; tl += 3) {
        int t = base + tl;
        const float4* xw = (const float4*)(xpad + t * WINc);  // 32B-aligned
        float acc = b2;
#pragma unroll
        for (int h4 = 0; h4 < 8; ++h4) {
          float4 xv = xw[h4];
          float4 wv = w2v[h4];
          acc = fmaf(xv.x, wv.x, acc);
          acc = fmaf(xv.y, wv.y, acc);
          acc = fmaf(xv.z, wv.z, acc);
          acc = fmaf(xv.w, wv.w, acc);
        }
        float sc = fminf(fmaxf(acc, 0.f), 6.f);
        sb[tl * NPAT + lane] = (sc - av0) + (float)t * CINV;
      }
    };

    // batched winner extraction for chunk cc, split across waves 1-3
    auto extract3 = [&](int cc) {
      unsigned int mv = bmbuf[cc & 1][lane];
      for (int i = wid - 1; i < TC; i += 3) {
        unsigned long long mk = __ballot(((mv >> i) & 1u) != 0u);
        int w = (int)(__ffsll(mk) - 1);
        if (lane == 0) idx8[cc * TC + i] = (unsigned char)w;
      }
    };

    fill(0, scb[0]);
    __syncthreads();  // S2

    for (int c = 0; c < NC; ++c) {
      if (c + 1 < NC) fill(c + 1, scb[(c + 1) & 1]);
      if (c >= 1) extract3(c - 1);
      __syncthreads();  // S3..S34
    }
    extract3(NC - 1);
    __syncthreads();  // S35
  }

  // ---- epilogue: out[b,l] = relu(shapes[l&7, idx[l>>3]] - x[b,l]) ----
  float4* outv = (float4*)(out + (size_t)b * Ll);
#pragma unroll
  for (int k = 0; k < 8; ++k) {
    int i4 = k * 256 + tid;
    int l0 = i4 * 4;
    int t  = l0 >> 3;
    int w0 = l0 & 7;
    int p  = (int)idx8[t];
    float4 o;
    o.x = fmaxf(shp[(w0 + 0) * NPAT + p] - xpad[HIST - 1 + l0 + 0], 0.f);
    o.y = fmaxf(shp[(w0 + 1) * NPAT + p] - xpad[HIST - 1 + l0 + 1], 0.f);
    o.z = fmaxf(shp[(w0 + 2) * NPAT + p] - xpad[HIST - 1 + l0 + 2], 0.f);
    o.w = fmaxf(shp[(w0 + 3) * NPAT + p] - xpad[HIST - 1 + l0 + 3], 0.f);
    outv[i4] = o;
  }
}

extern "C" void kernel_launch(void* const* d_in, const int* in_sizes, int n_in,
                              void* d_out, int out_size, void* d_ws, size_t ws_size,
                              hipStream_t stream) {
  const float* x        = (const float*)d_in[0];
  const float* avg_init = (const float*)d_in[1];
  const float* conv_w   = (const float*)d_in[2];
  const float* conv_b   = (const float*)d_in[3];
  const float* keys_w   = (const float*)d_in[4];
  const float* shapes_w = (const float*)d_in[5];
  float* wsf = (float*)d_ws;

  precompute_kernel<<<NPAT, 256, 0, stream>>>(conv_w, conv_b, keys_w, wsf);
  shaper_kernel<<<Bb, 256, 0, stream>>>(x, avg_init, shapes_w, wsf,
                                        (float*)d_out);
}